// Round 1
// baseline (628.051 us; speedup 1.0000x reference)
//
#include <hip/hip_runtime.h>

#define UNITS 4096
#define DEPTH 13
#define BATCH 256

typedef __attribute__((ext_vector_type(8))) short s16x8;
typedef __attribute__((ext_vector_type(4))) float f32x4;
typedef __attribute__((ext_vector_type(2))) float f32x2;

__device__ __forceinline__ unsigned short f2bf(float f){
  unsigned u = __builtin_bit_cast(unsigned, f);
  u += 0x7FFFu + ((u >> 16) & 1u);
  return (unsigned short)(u >> 16);
}
__device__ __forceinline__ int levelof(int j){ return j ? (32 - __clz(j)) : 0; }

// ---------------- K0: prep: W2 -> bf16, cumulative biases ----------------
__global__ __launch_bounds__(256) void k_prep(const float* __restrict__ W2,
    const float* __restrict__ b1, const float* __restrict__ b2, const float* __restrict__ b3,
    unsigned short* __restrict__ W2b, float* __restrict__ cb1, float* __restrict__ cb2,
    float* __restrict__ cb3){
  int g = blockIdx.x * 256 + threadIdx.x;
  if (g < DEPTH*64*64) W2b[g] = f2bf(W2[g]);   // keep [k][out][in] layout
  if (blockIdx.x == 0){
    int t = threadIdx.x;
    if (t < 64){
      float r = 0.f;
      cb1[t] = 0.f;                             // level 0: no terms for minheap=1
      for (int m = 1; m < DEPTH; ++m){ r += b1[(m-1)*64 + t]; cb1[m*64 + t] = r; }
      float r2 = 0.f;
      for (int m = 0; m < DEPTH; ++m){ r2 += b2[m*64 + t]; cb2[m*64 + t] = r2; }
    } else if (t < 66){
      int o = t - 64;
      float r = 0.f;
      for (int m = 0; m < DEPTH; ++m){ r += b3[m*2 + o]; cb3[m*2 + o] = r; }
    }
  }
}

// ---------------- K1: h1 = relu(heap_linear1(x)), bf16 store ----------------
// thread = (b, j, 8 features); writes 16B coalesced.
__global__ __launch_bounds__(256) void k_h1(const float* __restrict__ x,
    const float* __restrict__ W1, const float* __restrict__ cb1,
    unsigned short* __restrict__ h1){
  int g  = blockIdx.x * 256 + threadIdx.x;   // 8,388,608 threads
  int f0 = (g & 7) * 8;
  int bj = g >> 3;
  int j  = bj & (UNITS - 1);
  int b  = bj >> 12;
  int lvl = levelof(j);
  float acc[8];
  #pragma unroll
  for (int i = 0; i < 8; ++i) acc[i] = cb1[lvl*64 + f0 + i];
  const float* xb = x + (size_t)b * UNITS * 2;
  for (int k = 1; k <= lvl; ++k){
    int anc = j >> k;
    float x0 = xb[anc*2], x1 = xb[anc*2 + 1];
    const float* w = W1 + ((k-1)*64 + f0)*2;
    #pragma unroll
    for (int i = 0; i < 8; ++i) acc[i] = fmaf(w[2*i], x0, fmaf(w[2*i+1], x1, acc[i]));
  }
  s16x8 pack;
  #pragma unroll
  for (int i = 0; i < 8; ++i) pack[i] = (short)f2bf(fmaxf(acc[i], 0.f));
  *(s16x8*)(h1 + (size_t)bj*64 + f0) = pack;
}

// ---------------- K2: h2 via gathered MFMA GEMM + fused y3 epilogue ----------
// One block per node j. M=256 (all batch), N=64, K = 64*(lvl+1) gathered ancestors.
// A staged in LDS [256 x 128B], B = W2[k] [64 x 128B], both XOR-swizzled (T2).
__global__ __launch_bounds__(256) void k_h2y3(const unsigned short* __restrict__ h1,
    const unsigned short* __restrict__ W2b, const float* __restrict__ cb2,
    const float* __restrict__ W3, float* __restrict__ y3){
  __shared__ s16x8 As[2048];   // 32 KiB
  __shared__ s16x8 Bs[512];    //  8 KiB

  int bid  = blockIdx.x;
  // bijective XCD swizzle in 64-j runs: locality for near ancestors + level balance
  int slot = bid >> 3, xcd = bid & 7;
  int j    = (slot >> 6) * 512 + xcd * 64 + (slot & 63);
  int lvl  = levelof(j);

  int t    = threadIdx.x;
  int wid  = t >> 6, lane = t & 63;
  int l15  = lane & 15, kg = lane >> 4;

  f32x4 acc[4][4];
  #pragma unroll
  for (int m = 0; m < 4; ++m)
    #pragma unroll
    for (int n = 0; n < 4; ++n) acc[m][n] = (f32x4){0.f, 0.f, 0.f, 0.f};

  for (int k = 0; k <= lvl; ++k){
    int anc = j >> k;
    // stage A: 256 rows (batch) x 128B of h1[:, anc, :]
    #pragma unroll
    for (int i = 0; i < 8; ++i){
      int chunk = i*256 + t;                 // 2048 chunks of 16B
      int r     = chunk >> 3;
      int cB    = (chunk & 7) << 4;          // byte col in row
      const s16x8* src = (const s16x8*)(h1 + ((size_t)r*UNITS + anc)*64 + (cB >> 1));
      int dst = (r*128 + cB) ^ ((r & 7) << 4);
      As[dst >> 4] = *src;
    }
    // stage B: W2b[k] 64x64
    #pragma unroll
    for (int q = 0; q < 2; ++q){
      int chunk = t*2 + q;                   // 512 chunks
      int r     = chunk >> 3;
      int dst   = (chunk << 4) ^ ((r & 7) << 4);
      Bs[dst >> 4] = *(const s16x8*)(W2b + k*4096 + chunk*8);
    }
    __syncthreads();
    #pragma unroll
    for (int kk = 0; kk < 2; ++kk){
      s16x8 af[4];
      #pragma unroll
      for (int m = 0; m < 4; ++m){
        int row  = wid*64 + m*16 + l15;
        int byte = (row*128 + kk*64 + kg*16) ^ ((row & 7) << 4);
        af[m] = As[byte >> 4];
      }
      #pragma unroll
      for (int n = 0; n < 4; ++n){
        int bro  = n*16 + l15;
        int byte = (bro*128 + kk*64 + kg*16) ^ ((bro & 7) << 4);
        s16x8 bf = Bs[byte >> 4];
        #pragma unroll
        for (int m = 0; m < 4; ++m)
          acc[m][n] = __builtin_amdgcn_mfma_f32_16x16x32_bf16(af[m], bf, acc[m][n], 0, 0, 0);
      }
    }
    __syncthreads();
  }

  // epilogue: h2 = relu(acc + cb2) kept in regs; emit y3_k[j] = W3[k]*h2 for k<=12-lvl
  int nk3 = DEPTH - lvl;       // 13 - lvl
  float cbv[4];
  #pragma unroll
  for (int n = 0; n < 4; ++n) cbv[n] = cb2[lvl*64 + n*16 + l15];
  for (int m = 0; m < 4; ++m){
    for (int reg = 0; reg < 4; ++reg){
      int b = wid*64 + m*16 + kg*4 + reg;    // batch row (D: row=(lane>>4)*4+reg, col=lane&15)
      float hv[4];
      #pragma unroll
      for (int n = 0; n < 4; ++n) hv[n] = fmaxf(acc[m][n][reg] + cbv[n], 0.f);
      for (int k3 = 0; k3 < nk3; ++k3){
        float s0 = 0.f, s1 = 0.f;
        #pragma unroll
        for (int n = 0; n < 4; ++n){
          int f = n*16 + l15;
          s0 = fmaf(W3[(k3*2 + 0)*64 + f], hv[n], s0);
          s1 = fmaf(W3[(k3*2 + 1)*64 + f], hv[n], s1);
        }
        #pragma unroll
        for (int d = 1; d < 16; d <<= 1){
          s0 += __shfl_xor(s0, d);
          s1 += __shfl_xor(s1, d);
        }
        if (l15 == 0){
          int p = 8192 - (8192 >> k3) + j;   // pair index (k3, v=j)
          f32x2 v; v.x = s0; v.y = s1;
          *(f32x2*)(y3 + ((size_t)b*8191 + p)*2) = v;
        }
      }
    }
  }
}

// ---------------- K3: logits[b,j] = cb3[lvl] + sum_k y3[b, (k, j>>k)] -----------
__global__ __launch_bounds__(256) void k_out(const float* __restrict__ y3,
    const float* __restrict__ cb3, float* __restrict__ out){
  int g = blockIdx.x * 256 + threadIdx.x;    // 1,048,576 threads
  int j = g & (UNITS - 1);
  int b = g >> 12;
  int lvl = levelof(j);
  float s0 = cb3[lvl*2], s1 = cb3[lvl*2 + 1];
  const float* yb = y3 + (size_t)b * 8191 * 2;
  for (int k = 0; k <= lvl; ++k){
    int p = 8192 - (8192 >> k) + (j >> k);
    s0 += yb[p*2];
    s1 += yb[p*2 + 1];
  }
  out[(size_t)g*2]     = s0;
  out[(size_t)g*2 + 1] = s1;
}

extern "C" void kernel_launch(void* const* d_in, const int* in_sizes, int n_in,
                              void* d_out, int out_size, void* d_ws, size_t ws_size,
                              hipStream_t stream){
  const float* x  = (const float*)d_in[0];
  const float* W1 = (const float*)d_in[1];
  const float* b1 = (const float*)d_in[2];
  const float* W2 = (const float*)d_in[3];
  const float* b2 = (const float*)d_in[4];
  const float* W3 = (const float*)d_in[5];
  const float* b3 = (const float*)d_in[6];
  float* out = (float*)d_out;
  char* ws = (char*)d_ws;

  // workspace layout (256B aligned)
  unsigned short* W2b = (unsigned short*)(ws + 0);         // 106,496 B
  float* cb1 = (float*)(ws + 106496);                      //   3,328 B
  float* cb2 = (float*)(ws + 109824);                      //   3,328 B
  float* cb3 = (float*)(ws + 113152);                      //     104 B (padded)
  unsigned short* h1 = (unsigned short*)(ws + 113408);     // 134,217,728 B
  float* y3 = (float*)(ws + 113408 + (size_t)BATCH*UNITS*64*2);  // 16,775,168 B
  // total ~151.1 MB

  hipLaunchKernelGGL(k_prep, dim3(208),   dim3(256), 0, stream, W2, b1, b2, b3, W2b, cb1, cb2, cb3);
  hipLaunchKernelGGL(k_h1,   dim3(32768), dim3(256), 0, stream, x, W1, cb1, h1);
  hipLaunchKernelGGL(k_h2y3, dim3(4096),  dim3(256), 0, stream, h1, W2b, cb2, W3, y3);
  hipLaunchKernelGGL(k_out,  dim3(4096),  dim3(256), 0, stream, y3, cb3, out);
}